// Round 4
// baseline (1594.761 us; speedup 1.0000x reference)
//
#include <hip/hip_runtime.h>
#include <math.h>

#define Bv 8
#define Nv 2048
#define DIMv 1024
#define Hv 16
#define Dv 64
#define Rv 5
#define RMv 10

// output layout (flat concat, fp32)
#define ATTN_OFF 0
#define ESC_OFF (Bv * Nv * DIMv)              // 16777216
#define RSC_OFF (ESC_OFF + Bv * Hv * Nv * Rv) // 18087936
#define KL_OFF  (RSC_OFF + Bv * Hv * Nv * Rv) // 19398656

#define BMt 128      // rows per block
#define BK 64        // fp16 k-chunk
#define CT_STRIDE (128 + 4)

#define XHALFS (Bv * Nv * DIMv)     // 16777216
#define QKHALFS (2 * DIMv * DIMv)   // 2097152
#define NCONV ((XHALFS + QKHALFS) / 2048)  // 9216 convert blocks

using half8 = __attribute__((ext_vector_type(8))) _Float16;
using f32x4 = __attribute__((ext_vector_type(4))) float;

#define GLOAD(gp, lp)                                                      \
    __builtin_amdgcn_global_load_lds(                                      \
        (const __attribute__((address_space(1))) void*)(gp),               \
        (__attribute__((address_space(3))) void*)(lp), 16, 0, 0)

// ---- pre-pass: fp32 -> fp16 of x and qk_w into workspace; last block does kl
__global__ __launch_bounds__(256)
void convert_and_kl(const float* __restrict__ x, const float* __restrict__ qk,
                    _Float16* __restrict__ xh, _Float16* __restrict__ qkh,
                    const float* __restrict__ log_lam, const float* __restrict__ m_u,
                    const float* __restrict__ s_tri, const float* __restrict__ log_ssqrt,
                    float* __restrict__ out)
{
    const int t = threadIdx.x;
    if (blockIdx.x == NCONV) {
        // ---- kl reduction (verified round 1)
        __shared__ float red[256];
        float acc = 0.f;
        for (int idx = t; idx < Hv * Rv * Rv * Rv; idx += 256) {
            int hh = idx / 125;
            int rem = idx % 125;
            int a = rem / 25, u = (rem / 5) % 5, c = rem % 5;
            float S = 0.f;
            if (u == c)      S = expf(log_ssqrt[(hh * Rv + a) * Rv + u]);
            else if (u > c)  S = s_tri[((hh * Rv + a) * Rv + u) * Rv + c];
            float lam2 = expf(2.f * log_lam[hh * Rv + a]);
            float z = lam2 * S;
            acc += 0.5f * z * z;
        }
        for (int idx = t; idx < Hv * Rv * Rv; idx += 256) {
            int hh = idx / 25, a = (idx / 5) % 5;
            float e4 = expf(4.f * log_lam[hh * Rv + a]);
            float mu = m_u[idx];
            acc += 0.5f * e4 * mu * mu;
            acc -= log_ssqrt[idx];
        }
        for (int idx = t; idx < Hv * Rv; idx += 256) acc -= 2.f * (float)Rv * log_lam[idx];
        red[t] = acc;
        __syncthreads();
        for (int s = 128; s > 0; s >>= 1) {
            if (t < s) red[t] += red[t + s];
            __syncthreads();
        }
        if (t == 0) out[KL_OFF] = red[0] - 0.5f * (float)(Rv * Rv * Hv);
        return;
    }

    size_t i = ((size_t)blockIdx.x * 256 + t) * 8;
    const float* src;
    _Float16* dst;
    if (i < XHALFS) { src = x + i; dst = xh + i; }
    else            { src = qk + (i - XHALFS); dst = qkh + (i - XHALFS); }
    float4 v0 = *(const float4*)src;
    float4 v1 = *(const float4*)(src + 4);
    half8 hv = {(_Float16)v0.x, (_Float16)v0.y, (_Float16)v0.z, (_Float16)v0.w,
                (_Float16)v1.x, (_Float16)v1.y, (_Float16)v1.z, (_Float16)v1.w};
    *(half8*)dst = hv;
}

// grid: 2048 1-D (xcd-affine: id&7 -> heads {2x,2x+1}); block: 256 = 4 waves
__global__ __launch_bounds__(256, 4)
void svgp_main(const _Float16* __restrict__ xh, const _Float16* __restrict__ qkh,
               const float* __restrict__ x, const float* __restrict__ mask,
               const float* __restrict__ eps,
               const float* __restrict__ we_p, const float* __restrict__ wr_p,
               const float* __restrict__ log_lam, const float* __restrict__ m_u,
               const float* __restrict__ s_tri, const float* __restrict__ log_ssqrt,
               const float* __restrict__ fw_w, const float* __restrict__ fw_b,
               float* __restrict__ out)
{
    const int id = blockIdx.x;
    const int h = 2 * (id & 7) + ((id >> 3) & 1);
    const int rowTile = id >> 4;           // 0..127
    const int row0 = rowTile * BMt;        // flat row base (b*N + n)
    const int b0 = row0 >> 11;             // batch (tile never straddles b)
    const int t = threadIdx.x;
    const int lane = t & 63;
    const int w = t >> 6;
    const int wu = __builtin_amdgcn_readfirstlane(w);   // wave-uniform

    // LDS: staging A(16KB)+B(16KB) aliased with 64-row C chunk (64x132 fp32 = 33.8KB)
    __shared__ float smem[64 * CT_STRIDE];
    _Float16* sH = (_Float16*)smem;        // A slots [0,1024), B slots [1024,2048), 8 halfs each
    char* sBytes = (char*)smem;
    float (*sCt)[CT_STRIDE] = (float (*)[CT_STRIDE])smem;

    __shared__ float sS[Rv][Rv][Rv];
    __shared__ float sMu[Rv][Rv];
    __shared__ float sFw[Dv][Rv];
    __shared__ float sFb[Dv];
    __shared__ float sLam2[Rv];
    __shared__ float sWe[Dv][Rv];
    __shared__ float sWr[Dv][Rv];

    // ---- small tables (reads happen only after k-loop barriers)
    if (t < 125) {
        int a = t / 25, u = (t % 25) / 5, c = t % 5;
        float v = 0.f;
        if (u == c)      v = expf(log_ssqrt[(h * Rv + a) * Rv + u]);
        else if (u > c)  v = s_tri[((h * Rv + a) * Rv + u) * Rv + c];
        sS[a][u][c] = v;
    }
    if (t >= 128 && t < 153) { int i = t - 128; sMu[i / 5][i % 5] = m_u[h * Rv * Rv + i]; }
    if (t >= 160 && t < 165) sLam2[t - 160] = expf(2.f * log_lam[h * Rv + (t - 160)]);
    if (t >= 192 && t < 256) sFb[t - 192] = fw_b[t - 192];
    if (t < 320) sFw[t / Rv][t % Rv] = fw_w[t];
    { int t2 = t + 256; if (t2 < 320) sFw[t2 / Rv][t2 % Rv] = fw_w[t2]; }

    // ---- we/wr once per block (wave 0, lane = d), fp32
    if (t < 64) {
        float xv[RMv];
#pragma unroll
        for (int m = 0; m < RMv; ++m) {
            int nidx = (m == RMv - 1) ? (Nv - 1) : (int)((float)m * (2047.0f / 9.0f));
            xv[m] = x[((size_t)b0 * Nv + nidx) * DIMv + h * Dv + t];
        }
#pragma unroll
        for (int rr = 0; rr < Rv; ++rr) {
            float sw = 0.f, sr = 0.f;
#pragma unroll
            for (int m = 0; m < RMv; ++m) {
                sw = fmaf(xv[m], we_p[(h * RMv + m) * Rv + rr], sw);
                sr = fmaf(xv[m], wr_p[(h * RMv + m) * Rv + rr], sr);
            }
            sWe[t][rr] = sw; sWr[t][rr] = sr;
        }
    }

    // ---- staging address precompute (k0-invariant)
    size_t aOff[4], bOff[4];
    int ldsOffA[4], ldsOffB[4];
#pragma unroll
    for (int j = 0; j < 4; ++j) {
        int c = wu * 4 + j;
        int s = c * 64 + lane;
        int rl = ((s >> 7) << 4) + (s & 15);
        int ko = (s >> 4) & 7;
        aOff[j] = (size_t)(row0 + rl) * DIMv + ko * 8;
        int grow = (rl < 64) ? (h * Dv + rl) : (DIMv + h * Dv + (rl - 64));
        bOff[j] = (size_t)grow * DIMv + ko * 8;
        ldsOffA[j] = c * 1024;             // bytes
        ldsOffB[j] = 16384 + c * 1024;
    }

    const int wm = wu >> 1, wn = wu & 1;
    f32x4 acc[4][4];
#pragma unroll
    for (int i = 0; i < 4; ++i)
#pragma unroll
        for (int j = 0; j < 4; ++j) acc[i][j] = (f32x4){0.f, 0.f, 0.f, 0.f};

    for (int k0 = 0; k0 < DIMv; k0 += BK) {
#pragma unroll
        for (int j = 0; j < 4; ++j) GLOAD(xh + aOff[j] + k0, sBytes + ldsOffA[j]);
#pragma unroll
        for (int j = 0; j < 4; ++j) GLOAD(qkh + bOff[j] + k0, sBytes + ldsOffB[j]);
        __syncthreads();

#pragma unroll
        for (int kk = 0; kk < 2; ++kk) {
            const int fo = (kk * 4 + (lane >> 4)) * 16 + (lane & 15);
            half8 af[4], bf[4];
#pragma unroll
            for (int i = 0; i < 4; ++i)
                af[i] = *(half8*)(sH + ((wm * 4 + i) * 128 + fo) * 8);
#pragma unroll
            for (int j = 0; j < 4; ++j)
                bf[j] = *(half8*)(sH + (1024 + (wn * 4 + j) * 128 + fo) * 8);
#pragma unroll
            for (int i = 0; i < 4; ++i)
#pragma unroll
                for (int j = 0; j < 4; ++j)
                    acc[i][j] = __builtin_amdgcn_mfma_f32_16x16x32_f16(af[i], bf[j], acc[i][j], 0, 0, 0);
        }
        __syncthreads();
    }

    // ---- two-pass spill + epilogue over 64-row chunks (halves LDS footprint)
    const int rg = lane >> 4;
    const int dm = lane & 15;
    const int d0 = dm * 4;

    for (int pass = 0; pass < 2; ++pass) {
        // spill: waves whose row-half matches this pass
        if (wm == pass) {
#pragma unroll
            for (int i = 0; i < 4; ++i) {
                int rbase = i * 16 + (lane >> 4) * 4;
                int col = wn * 64 + (lane & 15);
#pragma unroll
                for (int j = 0; j < 4; ++j)
#pragma unroll
                    for (int reg = 0; reg < 4; ++reg)
                        sCt[rbase + reg][col + j * 16] = acc[i][j][reg];
            }
        }
        __syncthreads();

        for (int p = 0; p < 4; ++p) {
            const int rl = w * 16 + p * 4 + rg;      // local row 0..63
            const int nf = row0 + pass * 64 + rl;    // flat b*N+n
            const int n = nf & (Nv - 1);
            const float mk = mask[nf];

            float4 q4 = *(float4*)&sCt[rl][d0];
            float4 k4 = *(float4*)&sCt[rl][64 + d0];
            float qv[4] = {q4.x * mk, q4.y * mk, q4.z * mk, q4.w * mk};
            float kv[4] = {k4.x * mk, k4.y * mk, k4.z * mk, k4.w * mk};

            float red[12];
#pragma unroll
            for (int jj = 0; jj < 12; ++jj) red[jj] = 0.f;
#pragma unroll
            for (int i = 0; i < 4; ++i) {
                red[0] = fmaf(qv[i], qv[i], red[0]);
                red[1] = fmaf(kv[i], kv[i], red[1]);
#pragma unroll
                for (int rr = 0; rr < Rv; ++rr) {
                    red[2 + rr] = fmaf(qv[i], sWe[d0 + i][rr], red[2 + rr]);
                    red[7 + rr] = fmaf(kv[i], sWr[d0 + i][rr], red[7 + rr]);
                }
            }
#pragma unroll
            for (int off = 8; off > 0; off >>= 1) {
#pragma unroll
                for (int jj = 0; jj < 12; ++jj)
                    red[jj] += __shfl_xor(red[jj], off, 64);
            }
            const float qn = fmaxf(sqrtf(red[0]), 1e-12f);
            const float kn = fmaxf(sqrtf(red[1]), 1e-12f);

            float esc[Rv], rsc[Rv], v1[Rv];
#pragma unroll
            for (int rr = 0; rr < Rv; ++rr) {
                esc[rr] = red[2 + rr] / qn;
                rsc[rr] = red[7 + rr] / kn;
                v1[rr] = (esc[rr] + rsc[rr]) * sLam2[rr];
            }

            const size_t eb = (((size_t)(nf >> 11) * Hv + h) * Nv + n) * Rv;
            float ev[Rv];
#pragma unroll
            for (int u = 0; u < Rv; ++u) ev[u] = eps[eb + u];

            float smp[Rv];
#pragma unroll
            for (int c = 0; c < Rv; ++c) {
                float mn = 0.f;
#pragma unroll
                for (int a = 0; a < Rv; ++a) mn = fmaf(v1[a], sMu[a][c], mn);
                float nz = 0.f;
#pragma unroll
                for (int u = 0; u < Rv; ++u) {
                    float s = 0.f;
#pragma unroll
                    for (int a = 0; a < Rv; ++a) s = fmaf(v1[a], sS[a][u][c], s);
                    nz = fmaf(s, ev[u], nz);
                }
                smp[c] = mn + nz;
            }

            float4 ao;
            float aov[4];
#pragma unroll
            for (int i = 0; i < 4; ++i) {
                float a = sFb[d0 + i];
#pragma unroll
                for (int rr = 0; rr < Rv; ++rr) a = fmaf(smp[rr], sFw[d0 + i][rr], a);
                aov[i] = a;
            }
            ao.x = aov[0]; ao.y = aov[1]; ao.z = aov[2]; ao.w = aov[3];
            *(float4*)&out[ATTN_OFF + (size_t)nf * DIMv + h * Dv + d0] = ao;

            if (dm == 0) {
#pragma unroll
                for (int rr = 0; rr < Rv; ++rr) {
                    out[ESC_OFF + eb + rr] = esc[rr];
                    out[RSC_OFF + eb + rr] = rsc[rr];
                }
            }
        }
        __syncthreads();   // protect sCt before next pass's spill
    }
}

extern "C" void kernel_launch(void* const* d_in, const int* in_sizes, int n_in,
                              void* d_out, int out_size, void* d_ws, size_t ws_size,
                              hipStream_t stream) {
    const float* x        = (const float*)d_in[0];
    const float* mask     = (const float*)d_in[1];
    const float* eps      = (const float*)d_in[2];
    const float* qk_w     = (const float*)d_in[3];
    const float* we_p     = (const float*)d_in[4];
    const float* wr_p     = (const float*)d_in[5];
    const float* log_lam  = (const float*)d_in[6];
    const float* m_u      = (const float*)d_in[7];
    const float* s_tri    = (const float*)d_in[8];
    const float* log_ssqrt= (const float*)d_in[9];
    const float* fw_w     = (const float*)d_in[10];
    const float* fw_b     = (const float*)d_in[11];
    float* out = (float*)d_out;

    _Float16* xh  = (_Float16*)d_ws;
    _Float16* qkh = xh + XHALFS;

    convert_and_kl<<<dim3(NCONV + 1), 256, 0, stream>>>(x, qk_w, xh, qkh,
                                                        log_lam, m_u, s_tri, log_ssqrt, out);
    svgp_main<<<dim3(2048), 256, 0, stream>>>(xh, qkh, x, mask, eps, we_p, wr_p,
                                              log_lam, m_u, s_tri, log_ssqrt, fw_w, fw_b, out);
}

// Round 5
// 634.887 us; speedup vs baseline: 2.5119x; 2.5119x over previous
//
#include <hip/hip_runtime.h>
#include <math.h>

#define Bv 8
#define Nv 2048
#define DIMv 1024
#define Hv 16
#define Dv 64
#define Rv 5
#define RMv 10

// output layout (flat concat, fp32)
#define ATTN_OFF 0
#define ESC_OFF (Bv * Nv * DIMv)              // 16777216
#define RSC_OFF (ESC_OFF + Bv * Hv * Nv * Rv) // 18087936
#define KL_OFF  (RSC_OFF + Bv * Hv * Nv * Rv) // 19398656

#define BMt 128      // rows per block
#define BK 64        // fp16 k-chunk
#define CT_STRIDE (128 + 4)

#define XHALFS (Bv * Nv * DIMv)     // 16777216
#define QKHALFS (2 * DIMv * DIMv)   // 2097152
#define NCONV ((XHALFS + QKHALFS) / 2048)  // 9216 convert blocks

using half8 = __attribute__((ext_vector_type(8))) _Float16;
using f32x4 = __attribute__((ext_vector_type(4))) float;

#define GLOAD(gp, lp)                                                      \
    __builtin_amdgcn_global_load_lds(                                      \
        (const __attribute__((address_space(1))) void*)(gp),               \
        (__attribute__((address_space(3))) void*)(lp), 16, 0, 0)

// ---- pre-pass: fp32 -> fp16 of x and qk_w into workspace; last block does kl
__global__ __launch_bounds__(256)
void convert_and_kl(const float* __restrict__ x, const float* __restrict__ qk,
                    _Float16* __restrict__ xh, _Float16* __restrict__ qkh,
                    const float* __restrict__ log_lam, const float* __restrict__ m_u,
                    const float* __restrict__ s_tri, const float* __restrict__ log_ssqrt,
                    float* __restrict__ out)
{
    const int t = threadIdx.x;
    if (blockIdx.x == NCONV) {
        __shared__ float red[256];
        float acc = 0.f;
        for (int idx = t; idx < Hv * Rv * Rv * Rv; idx += 256) {
            int hh = idx / 125;
            int rem = idx % 125;
            int a = rem / 25, u = (rem / 5) % 5, c = rem % 5;
            float S = 0.f;
            if (u == c)      S = expf(log_ssqrt[(hh * Rv + a) * Rv + u]);
            else if (u > c)  S = s_tri[((hh * Rv + a) * Rv + u) * Rv + c];
            float lam2 = expf(2.f * log_lam[hh * Rv + a]);
            float z = lam2 * S;
            acc += 0.5f * z * z;
        }
        for (int idx = t; idx < Hv * Rv * Rv; idx += 256) {
            int hh = idx / 25, a = (idx / 5) % 5;
            float e4 = expf(4.f * log_lam[hh * Rv + a]);
            float mu = m_u[idx];
            acc += 0.5f * e4 * mu * mu;
            acc -= log_ssqrt[idx];
        }
        for (int idx = t; idx < Hv * Rv; idx += 256) acc -= 2.f * (float)Rv * log_lam[idx];
        red[t] = acc;
        __syncthreads();
        for (int s = 128; s > 0; s >>= 1) {
            if (t < s) red[t] += red[t + s];
            __syncthreads();
        }
        if (t == 0) out[KL_OFF] = red[0] - 0.5f * (float)(Rv * Rv * Hv);
        return;
    }

    size_t i = ((size_t)blockIdx.x * 256 + t) * 8;
    const float* src;
    _Float16* dst;
    if (i < XHALFS) { src = x + i; dst = xh + i; }
    else            { src = qk + (i - XHALFS); dst = qkh + (i - XHALFS); }
    float4 v0 = *(const float4*)src;
    float4 v1 = *(const float4*)(src + 4);
    half8 hv = {(_Float16)v0.x, (_Float16)v0.y, (_Float16)v0.z, (_Float16)v0.w,
                (_Float16)v1.x, (_Float16)v1.y, (_Float16)v1.z, (_Float16)v1.w};
    *(half8*)dst = hv;
}

// grid: 2048 1-D (xcd-affine: id&7 -> heads {2x,2x+1}); block: 256 = 4 waves
// launch_bounds (256,2): natural VGPR = 128 (no spills) -> 4 waves/SIMD by VGPR,
// 4 blocks/CU by LDS (38.9 KB). (256,4) forced 64 VGPR -> catastrophic scratch
// spills (round 4: 4.9 GB spill traffic).
__global__ __launch_bounds__(256, 2)
void svgp_main(const _Float16* __restrict__ xh, const _Float16* __restrict__ qkh,
               const float* __restrict__ x, const float* __restrict__ mask,
               const float* __restrict__ eps,
               const float* __restrict__ we_p, const float* __restrict__ wr_p,
               const float* __restrict__ log_lam, const float* __restrict__ m_u,
               const float* __restrict__ s_tri, const float* __restrict__ log_ssqrt,
               const float* __restrict__ fw_w, const float* __restrict__ fw_b,
               float* __restrict__ out)
{
    const int id = blockIdx.x;
    const int h = 2 * (id & 7) + ((id >> 3) & 1);
    const int rowTile = id >> 4;           // 0..127
    const int row0 = rowTile * BMt;        // flat row base (b*N + n)
    const int b0 = row0 >> 11;             // batch (tile never straddles b)
    const int t = threadIdx.x;
    const int lane = t & 63;
    const int w = t >> 6;
    const int wu = __builtin_amdgcn_readfirstlane(w);   // wave-uniform

    // LDS: staging A(16KB)+B(16KB) aliased with 64-row C chunk (64x132 fp32 = 33.8KB)
    __shared__ float smem[64 * CT_STRIDE];
    _Float16* sH = (_Float16*)smem;
    char* sBytes = (char*)smem;
    float (*sCt)[CT_STRIDE] = (float (*)[CT_STRIDE])smem;

    __shared__ float sS[Rv][Rv][Rv];
    __shared__ float sMu[Rv][Rv];
    __shared__ float sFw[Dv][Rv];
    __shared__ float sFb[Dv];
    __shared__ float sLam2[Rv];
    __shared__ float sWe[Dv][Rv];
    __shared__ float sWr[Dv][Rv];

    // ---- small tables (reads happen only after k-loop barriers)
    if (t < 125) {
        int a = t / 25, u = (t % 25) / 5, c = t % 5;
        float v = 0.f;
        if (u == c)      v = expf(log_ssqrt[(h * Rv + a) * Rv + u]);
        else if (u > c)  v = s_tri[((h * Rv + a) * Rv + u) * Rv + c];
        sS[a][u][c] = v;
    }
    if (t >= 128 && t < 153) { int i = t - 128; sMu[i / 5][i % 5] = m_u[h * Rv * Rv + i]; }
    if (t >= 160 && t < 165) sLam2[t - 160] = expf(2.f * log_lam[h * Rv + (t - 160)]);
    if (t >= 192 && t < 256) sFb[t - 192] = fw_b[t - 192];
    if (t < 320) sFw[t / Rv][t % Rv] = fw_w[t];
    { int t2 = t + 256; if (t2 < 320) sFw[t2 / Rv][t2 % Rv] = fw_w[t2]; }

    // ---- we/wr once per block (wave 0, lane = d), fp32
    if (t < 64) {
        float xv[RMv];
#pragma unroll
        for (int m = 0; m < RMv; ++m) {
            int nidx = (m == RMv - 1) ? (Nv - 1) : (int)((float)m * (2047.0f / 9.0f));
            xv[m] = x[((size_t)b0 * Nv + nidx) * DIMv + h * Dv + t];
        }
#pragma unroll
        for (int rr = 0; rr < Rv; ++rr) {
            float sw = 0.f, sr = 0.f;
#pragma unroll
            for (int m = 0; m < RMv; ++m) {
                sw = fmaf(xv[m], we_p[(h * RMv + m) * Rv + rr], sw);
                sr = fmaf(xv[m], wr_p[(h * RMv + m) * Rv + rr], sr);
            }
            sWe[t][rr] = sw; sWr[t][rr] = sr;
        }
    }

    // ---- staging address precompute (k0-invariant)
    size_t aOff[4], bOff[4];
    int ldsOffA[4], ldsOffB[4];
#pragma unroll
    for (int j = 0; j < 4; ++j) {
        int c = wu * 4 + j;
        int s = c * 64 + lane;
        int rl = ((s >> 7) << 4) + (s & 15);
        int ko = (s >> 4) & 7;
        aOff[j] = (size_t)(row0 + rl) * DIMv + ko * 8;
        int grow = (rl < 64) ? (h * Dv + rl) : (DIMv + h * Dv + (rl - 64));
        bOff[j] = (size_t)grow * DIMv + ko * 8;
        ldsOffA[j] = c * 1024;             // bytes
        ldsOffB[j] = 16384 + c * 1024;
    }

    const int wm = wu >> 1, wn = wu & 1;
    f32x4 acc[4][4];
#pragma unroll
    for (int i = 0; i < 4; ++i)
#pragma unroll
        for (int j = 0; j < 4; ++j) acc[i][j] = (f32x4){0.f, 0.f, 0.f, 0.f};

    for (int k0 = 0; k0 < DIMv; k0 += BK) {
#pragma unroll
        for (int j = 0; j < 4; ++j) GLOAD(xh + aOff[j] + k0, sBytes + ldsOffA[j]);
#pragma unroll
        for (int j = 0; j < 4; ++j) GLOAD(qkh + bOff[j] + k0, sBytes + ldsOffB[j]);
        __syncthreads();

#pragma unroll
        for (int kk = 0; kk < 2; ++kk) {
            const int fo = (kk * 4 + (lane >> 4)) * 16 + (lane & 15);
            half8 af[4], bf[4];
#pragma unroll
            for (int i = 0; i < 4; ++i)
                af[i] = *(half8*)(sH + ((wm * 4 + i) * 128 + fo) * 8);
#pragma unroll
            for (int j = 0; j < 4; ++j)
                bf[j] = *(half8*)(sH + (1024 + (wn * 4 + j) * 128 + fo) * 8);
#pragma unroll
            for (int i = 0; i < 4; ++i)
#pragma unroll
                for (int j = 0; j < 4; ++j)
                    acc[i][j] = __builtin_amdgcn_mfma_f32_16x16x32_f16(af[i], bf[j], acc[i][j], 0, 0, 0);
        }
        __syncthreads();
    }

    // ---- two-pass spill + epilogue over 64-row chunks (halves LDS footprint)
    const int rg = lane >> 4;
    const int dm = lane & 15;
    const int d0 = dm * 4;

    for (int pass = 0; pass < 2; ++pass) {
        if (wm == pass) {
#pragma unroll
            for (int i = 0; i < 4; ++i) {
                int rbase = i * 16 + (lane >> 4) * 4;
                int col = wn * 64 + (lane & 15);
#pragma unroll
                for (int j = 0; j < 4; ++j)
#pragma unroll
                    for (int reg = 0; reg < 4; ++reg)
                        sCt[rbase + reg][col + j * 16] = acc[i][j][reg];
            }
        }
        __syncthreads();

        for (int p = 0; p < 4; ++p) {
            const int rl = w * 16 + p * 4 + rg;      // local row 0..63
            const int nf = row0 + pass * 64 + rl;    // flat b*N+n
            const int n = nf & (Nv - 1);
            const float mk = mask[nf];

            float4 q4 = *(float4*)&sCt[rl][d0];
            float4 k4 = *(float4*)&sCt[rl][64 + d0];
            float qv[4] = {q4.x * mk, q4.y * mk, q4.z * mk, q4.w * mk};
            float kv[4] = {k4.x * mk, k4.y * mk, k4.z * mk, k4.w * mk};

            float red[12];
#pragma unroll
            for (int jj = 0; jj < 12; ++jj) red[jj] = 0.f;
#pragma unroll
            for (int i = 0; i < 4; ++i) {
                red[0] = fmaf(qv[i], qv[i], red[0]);
                red[1] = fmaf(kv[i], kv[i], red[1]);
#pragma unroll
                for (int rr = 0; rr < Rv; ++rr) {
                    red[2 + rr] = fmaf(qv[i], sWe[d0 + i][rr], red[2 + rr]);
                    red[7 + rr] = fmaf(kv[i], sWr[d0 + i][rr], red[7 + rr]);
                }
            }
#pragma unroll
            for (int off = 8; off > 0; off >>= 1) {
#pragma unroll
                for (int jj = 0; jj < 12; ++jj)
                    red[jj] += __shfl_xor(red[jj], off, 64);
            }
            const float qn = fmaxf(sqrtf(red[0]), 1e-12f);
            const float kn = fmaxf(sqrtf(red[1]), 1e-12f);

            float esc[Rv], rsc[Rv], v1[Rv];
#pragma unroll
            for (int rr = 0; rr < Rv; ++rr) {
                esc[rr] = red[2 + rr] / qn;
                rsc[rr] = red[7 + rr] / kn;
                v1[rr] = (esc[rr] + rsc[rr]) * sLam2[rr];
            }

            const size_t eb = (((size_t)(nf >> 11) * Hv + h) * Nv + n) * Rv;
            float ev[Rv];
#pragma unroll
            for (int u = 0; u < Rv; ++u) ev[u] = eps[eb + u];

            float smp[Rv];
#pragma unroll
            for (int c = 0; c < Rv; ++c) {
                float mn = 0.f;
#pragma unroll
                for (int a = 0; a < Rv; ++a) mn = fmaf(v1[a], sMu[a][c], mn);
                float nz = 0.f;
#pragma unroll
                for (int u = 0; u < Rv; ++u) {
                    float s = 0.f;
#pragma unroll
                    for (int a = 0; a < Rv; ++a) s = fmaf(v1[a], sS[a][u][c], s);
                    nz = fmaf(s, ev[u], nz);
                }
                smp[c] = mn + nz;
            }

            float4 ao;
            float aov[4];
#pragma unroll
            for (int i = 0; i < 4; ++i) {
                float a = sFb[d0 + i];
#pragma unroll
                for (int rr = 0; rr < Rv; ++rr) a = fmaf(smp[rr], sFw[d0 + i][rr], a);
                aov[i] = a;
            }
            ao.x = aov[0]; ao.y = aov[1]; ao.z = aov[2]; ao.w = aov[3];
            *(float4*)&out[ATTN_OFF + (size_t)nf * DIMv + h * Dv + d0] = ao;

            if (dm == 0) {
#pragma unroll
                for (int rr = 0; rr < Rv; ++rr) {
                    out[ESC_OFF + eb + rr] = esc[rr];
                    out[RSC_OFF + eb + rr] = rsc[rr];
                }
            }
        }
        __syncthreads();   // protect sCt before next pass's spill
    }
}

extern "C" void kernel_launch(void* const* d_in, const int* in_sizes, int n_in,
                              void* d_out, int out_size, void* d_ws, size_t ws_size,
                              hipStream_t stream) {
    const float* x        = (const float*)d_in[0];
    const float* mask     = (const float*)d_in[1];
    const float* eps      = (const float*)d_in[2];
    const float* qk_w     = (const float*)d_in[3];
    const float* we_p     = (const float*)d_in[4];
    const float* wr_p     = (const float*)d_in[5];
    const float* log_lam  = (const float*)d_in[6];
    const float* m_u      = (const float*)d_in[7];
    const float* s_tri    = (const float*)d_in[8];
    const float* log_ssqrt= (const float*)d_in[9];
    const float* fw_w     = (const float*)d_in[10];
    const float* fw_b     = (const float*)d_in[11];
    float* out = (float*)d_out;

    _Float16* xh  = (_Float16*)d_ws;
    _Float16* qkh = xh + XHALFS;

    convert_and_kl<<<dim3(NCONV + 1), 256, 0, stream>>>(x, qk_w, xh, qkh,
                                                        log_lam, m_u, s_tri, log_ssqrt, out);
    svgp_main<<<dim3(2048), 256, 0, stream>>>(xh, qkh, x, mask, eps, we_p, wr_p,
                                              log_lam, m_u, s_tri, log_ssqrt, fw_w, fw_b, out);
}